// Round 1
// baseline (276.154 us; speedup 1.0000x reference)
//
#include <hip/hip_runtime.h>
#include <math.h>

// MiniS4D: B=8, H=512 (d_model), N=64 (d_state), L=1024
// ws float layout:
//   [0..6)*32768 : params rr, ri, rinvr, rinvi, cr, ci   (each [H][N])
//   Y at 6*32768, size 8*512*1024
//   partial at Y+8*512*1024, size 512 (=[b][og][lg])

constexpr int Hm = 512, Ns = 64, Lm = 1024, Bm = 8;
constexpr int PAR = Hm * Ns; // 32768

__global__ void k0_params(const float* __restrict__ log_dt,
                          const float* __restrict__ log_A_real,
                          const float* __restrict__ A_imag,
                          const float* __restrict__ B_real,
                          const float* __restrict__ B_imag,
                          const float* __restrict__ C_real,
                          const float* __restrict__ C_imag,
                          float* __restrict__ ws) {
    int idx = blockIdx.x * blockDim.x + threadIdx.x;
    if (idx >= PAR) return;
    int h = idx >> 6;
    double dt = exp((double)log_dt[h]);
    double Ar = -exp((double)log_A_real[idx]);
    double Ai = (double)A_imag[idx];
    double ar = Ar * dt, ai = Ai * dt;          // dtA
    double er = exp(ar);
    double rr = er * cos(ai), ri = er * sin(ai);        // r = exp(dtA)
    double eri = exp(-ar);
    double vr = eri * cos(ai), vi = -eri * sin(ai);     // r^-1 = exp(-dtA)
    // B_bar = (r - 1)/A * Bc
    double nr = rr - 1.0, ni = ri;
    double den = Ar * Ar + Ai * Ai;
    double qr = (nr * Ar + ni * Ai) / den;
    double qi = (ni * Ar - nr * Ai) / den;
    double Br = (double)B_real[idx], Bi = (double)B_imag[idx];
    double bbr = qr * Br - qi * Bi, bbi = qr * Bi + qi * Br;
    double Cr = (double)C_real[idx], Ci = (double)C_imag[idx];
    double wr = Cr * bbr - Ci * bbi, wi = Cr * bbi + Ci * bbr;
    // c = w * r^(L-1)  (double trig: phase up to ~2e4 rad)
    double e2 = exp(ar * (double)(Lm - 1));
    double ph = ai * (double)(Lm - 1);
    double pr = e2 * cos(ph), pi = e2 * sin(ph);
    double cr = wr * pr - wi * pi, ci = wr * pi + wi * pr;
    ws[0 * PAR + idx] = (float)rr;
    ws[1 * PAR + idx] = (float)ri;
    ws[2 * PAR + idx] = (float)vr;
    ws[3 * PAR + idx] = (float)vi;
    ws[4 * PAR + idx] = (float)cr;
    ws[5 * PAR + idx] = (float)ci;
}

// One wave per (b,h). lane = state n. y[t] = Re(sum_n h_n[t] * P_n[t]),
// P[t] = sum_{s<=t} r^s u[s] (stable), h[t] = w * r^(L-1-t) (grows to |w|).
__global__ __launch_bounds__(128) void k1_scan(const float* __restrict__ u,
                                               const float* __restrict__ Dvec,
                                               const float* __restrict__ ws,
                                               float* __restrict__ Y) {
    __shared__ float lds[2][64][65]; // [wave][n][t], stride 65 -> conflict-free
    const int lane = threadIdx.x & 63;
    const int wid = threadIdx.x >> 6;
    const int pair = blockIdx.x * 2 + wid;   // b*512 + h
    const int b = pair >> 9, h = pair & 511;
    const int pidx = h * 64 + lane;
    const float rr = ws[0 * PAR + pidx], ri = ws[1 * PAR + pidx];
    const float vr = ws[2 * PAR + pidx], vi = ws[3 * PAR + pidx];
    float hr = ws[4 * PAR + pidx], hi = ws[5 * PAR + pidx];
    float qr = 1.f, qi = 0.f, Pr = 0.f, Pi = 0.f;
    const float Dh = Dvec[h];
    const float* ub = u + (size_t)pair * Lm;
    float* yb = Y + (size_t)pair * Lm;

    for (int ch = 0; ch < 16; ++ch) {
        float ureg = ub[ch * 64 + lane];
        #pragma unroll
        for (int t = 0; t < 64; ++t) {
            float uv = __int_as_float(
                __builtin_amdgcn_readlane(__float_as_int(ureg), t));
            Pr = fmaf(qr, uv, Pr);
            Pi = fmaf(qi, uv, Pi);
            lds[wid][lane][t] = hr * Pr - hi * Pi;
            float tq = qr * rr - qi * ri;
            qi = fmaf(qr, ri, qi * rr);
            qr = tq;
            float th = hr * vr - hi * vi;
            hi = fmaf(hr, vi, hi * vr);
            hr = th;
        }
        __syncthreads();
        // lane plays role of t: sum over n (4 partials to shorten dep chain)
        float s0 = 0.f, s1 = 0.f, s2 = 0.f, s3 = 0.f;
        #pragma unroll
        for (int n = 0; n < 64; n += 4) {
            s0 += lds[wid][n + 0][lane];
            s1 += lds[wid][n + 1][lane];
            s2 += lds[wid][n + 2][lane];
            s3 += lds[wid][n + 3][lane];
        }
        float yv = fmaf(Dh, ureg, (s0 + s1) + (s2 + s3));
        float g = 0.5f * yv * (1.0f + erff(yv * 0.70710678118654752f));
        yb[ch * 64 + lane] = g;
        __syncthreads();
    }
}

// z = conv_w @ Y (+b), GLU, mean over l, * dec_w -> per-block partial scalar.
// Block: (b, og: 64 output-chan pairs, lg: 128 l's). 256 threads, 4x4 micro.
__global__ __launch_bounds__(256) void k2_gemm(const float* __restrict__ Y,
                                               const float* __restrict__ conv_w,
                                               const float* __restrict__ conv_b,
                                               const float* __restrict__ dec_w,
                                               float* __restrict__ partial) {
    __shared__ float Wa[16][68];
    __shared__ float Wb[16][68];
    __shared__ float Yt[16][68];
    __shared__ float red[64][17];
    const int tid = threadIdx.x;
    const int gb = blockIdx.x;
    const int b = gb >> 6;
    const int rem = gb & 63;
    const int og = rem >> 3, lg = rem & 7;
    const int o0 = og * 64;
    const int to = tid >> 4, tl = tid & 15;

    float pacc[4] = {0.f, 0.f, 0.f, 0.f};

    for (int half = 0; half < 2; ++half) {
        const int l0 = lg * 128 + half * 64;
        float acc_a[4][4];
        float acc_b[4][4];
        #pragma unroll
        for (int i = 0; i < 4; ++i)
            #pragma unroll
            for (int j = 0; j < 4; ++j) { acc_a[i][j] = 0.f; acc_b[i][j] = 0.f; }

        for (int c0 = 0; c0 < 512; c0 += 16) {
            __syncthreads();
            {
                const int ot = tid >> 2, cq = tid & 3;
                float4 wa4 = *(const float4*)&conv_w[(size_t)(o0 + ot) * 512 + c0 + cq * 4];
                float4 wb4 = *(const float4*)&conv_w[(size_t)(o0 + ot + 512) * 512 + c0 + cq * 4];
                Wa[cq * 4 + 0][ot] = wa4.x; Wa[cq * 4 + 1][ot] = wa4.y;
                Wa[cq * 4 + 2][ot] = wa4.z; Wa[cq * 4 + 3][ot] = wa4.w;
                Wb[cq * 4 + 0][ot] = wb4.x; Wb[cq * 4 + 1][ot] = wb4.y;
                Wb[cq * 4 + 2][ot] = wb4.z; Wb[cq * 4 + 3][ot] = wb4.w;
                const int ct = tid >> 4, lt = (tid & 15) * 4;
                float4 yv4 = *(const float4*)&Y[((size_t)b * 512 + c0 + ct) * 1024 + l0 + lt];
                *(float4*)&Yt[ct][lt] = yv4;
            }
            __syncthreads();
            #pragma unroll
            for (int cc = 0; cc < 16; ++cc) {
                float4 wa4 = *(const float4*)&Wa[cc][to * 4];
                float4 wb4 = *(const float4*)&Wb[cc][to * 4];
                float4 yv4 = *(const float4*)&Yt[cc][tl * 4];
                float wa[4] = {wa4.x, wa4.y, wa4.z, wa4.w};
                float wb[4] = {wb4.x, wb4.y, wb4.z, wb4.w};
                float yv[4] = {yv4.x, yv4.y, yv4.z, yv4.w};
                #pragma unroll
                for (int i = 0; i < 4; ++i)
                    #pragma unroll
                    for (int j = 0; j < 4; ++j) {
                        acc_a[i][j] = fmaf(wa[i], yv[j], acc_a[i][j]);
                        acc_b[i][j] = fmaf(wb[i], yv[j], acc_b[i][j]);
                    }
            }
        }
        #pragma unroll
        for (int i = 0; i < 4; ++i) {
            const float cba = conv_b[o0 + to * 4 + i];
            const float cbb = conv_b[512 + o0 + to * 4 + i];
            #pragma unroll
            for (int j = 0; j < 4; ++j) {
                float za = acc_a[i][j] + cba;
                float zb = acc_b[i][j] + cbb;
                float sg = 1.0f / (1.0f + expf(-zb));
                pacc[i] += za * sg;
            }
        }
    }

    __syncthreads();
    #pragma unroll
    for (int i = 0; i < 4; ++i) red[to * 4 + i][tl] = pacc[i];
    __syncthreads();
    if (tid < 64) {
        float s = 0.f;
        #pragma unroll
        for (int j = 0; j < 16; ++j) s += red[tid][j];
        float val = s * dec_w[o0 + tid] * (1.0f / 1024.0f);
        #pragma unroll
        for (int off = 32; off; off >>= 1) val += __shfl_xor(val, off);
        if (tid == 0) partial[(b * 8 + og) * 8 + lg] = val;
    }
}

__global__ void k3_final(const float* __restrict__ partial,
                         const float* __restrict__ dec_b,
                         float* __restrict__ out) {
    int b = threadIdx.x;
    if (b < Bm) {
        float s = dec_b[0];
        for (int i = 0; i < 64; ++i) s += partial[b * 64 + i];
        out[b] = s;
    }
}

extern "C" void kernel_launch(void* const* d_in, const int* in_sizes, int n_in,
                              void* d_out, int out_size, void* d_ws, size_t ws_size,
                              hipStream_t stream) {
    const float* u          = (const float*)d_in[0];
    const float* log_dt     = (const float*)d_in[1];
    const float* log_A_real = (const float*)d_in[2];
    const float* A_imag     = (const float*)d_in[3];
    const float* B_real     = (const float*)d_in[4];
    const float* B_imag     = (const float*)d_in[5];
    const float* C_real     = (const float*)d_in[6];
    const float* C_imag     = (const float*)d_in[7];
    const float* Dvec       = (const float*)d_in[8];
    const float* conv_w     = (const float*)d_in[9];
    const float* conv_b     = (const float*)d_in[10];
    const float* dec_w      = (const float*)d_in[11];
    const float* dec_b      = (const float*)d_in[12];
    float* ws = (float*)d_ws;
    float* Y = ws + 6 * PAR;
    float* partial = Y + (size_t)Bm * Hm * Lm;
    float* out = (float*)d_out;

    k0_params<<<128, 256, 0, stream>>>(log_dt, log_A_real, A_imag, B_real,
                                       B_imag, C_real, C_imag, ws);
    k1_scan<<<2048, 128, 0, stream>>>(u, Dvec, ws, Y);
    k2_gemm<<<512, 256, 0, stream>>>(Y, conv_w, conv_b, dec_w, partial);
    k3_final<<<1, 64, 0, stream>>>(partial, dec_b, out);
}

// Round 4
// 196.464 us; speedup vs baseline: 1.4056x; 1.4056x over previous
//
#include <hip/hip_runtime.h>
#include <hip/hip_bf16.h>
#include <math.h>

typedef __attribute__((ext_vector_type(8))) short short8;
typedef __attribute__((ext_vector_type(4))) float f32x4;

constexpr int Hm = 512, Lm = 1024, Bm = 8;
constexpr int PAR = Hm * 64;
constexpr size_t PLANE = (size_t)Bm * Hm * Lm;   // 4194304 ushorts per plane

static __device__ __forceinline__ unsigned short f2bf(float f) {
    __hip_bfloat16 h = __float2bfloat16(f);
    return *reinterpret_cast<unsigned short*>(&h);
}
static __device__ __forceinline__ float bf2f(unsigned short u) {
    return __uint_as_float((unsigned)u << 16);
}

// r = exp(dtA), rinv = exp(-dtA), c = w * r^(L-1), w = Cc*B_bar  (R1-proven)
__global__ void k0_params(const float* __restrict__ log_dt,
                          const float* __restrict__ log_A_real,
                          const float* __restrict__ A_imag,
                          const float* __restrict__ B_real,
                          const float* __restrict__ B_imag,
                          const float* __restrict__ C_real,
                          const float* __restrict__ C_imag,
                          float* __restrict__ par) {
    int idx = blockIdx.x * blockDim.x + threadIdx.x;
    if (idx >= PAR) return;
    int h = idx >> 6;
    double dt = exp((double)log_dt[h]);
    double Ar = -exp((double)log_A_real[idx]);
    double Ai = (double)A_imag[idx];
    double ar = Ar * dt, ai = Ai * dt;          // dtA
    double er = exp(ar);
    double rr = er * cos(ai), ri = er * sin(ai);        // r
    double eri = exp(-ar);
    double vr = eri * cos(ai), vi = -eri * sin(ai);     // r^-1
    double nr = rr - 1.0, ni = ri;
    double den = Ar * Ar + Ai * Ai;
    double qr = (nr * Ar + ni * Ai) / den;
    double qi = (ni * Ar - nr * Ai) / den;
    double Br = (double)B_real[idx], Bi = (double)B_imag[idx];
    double bbr = qr * Br - qi * Bi, bbi = qr * Bi + qi * Br;
    double Cr = (double)C_real[idx], Ci = (double)C_imag[idx];
    double wr = Cr * bbr - Ci * bbi, wi = Cr * bbi + Ci * bbr;
    double e2 = exp(ar * (double)(Lm - 1));
    double ph = ai * (double)(Lm - 1);
    double pr = e2 * cos(ph), pi = e2 * sin(ph);
    double cr = wr * pr - wi * pi, ci = wr * pi + wi * pr;
    par[0 * PAR + idx] = (float)rr;
    par[1 * PAR + idx] = (float)ri;
    par[2 * PAR + idx] = (float)vr;
    par[3 * PAR + idx] = (float)vi;
    par[4 * PAR + idx] = (float)cr;
    par[5 * PAR + idx] = (float)ci;
}

// conv_w f32 -> hi/lo bf16 planes
__global__ void k_cvt(const float* __restrict__ w,
                      unsigned short* __restrict__ oh,
                      unsigned short* __restrict__ ol) {
    int i = (blockIdx.x * 256 + threadIdx.x) * 4;
    float4 v = *(const float4*)&w[i];
    unsigned short h0 = f2bf(v.x), h1 = f2bf(v.y), h2 = f2bf(v.z), h3 = f2bf(v.w);
    unsigned short l0 = f2bf(v.x - bf2f(h0));
    unsigned short l1 = f2bf(v.y - bf2f(h1));
    unsigned short l2 = f2bf(v.z - bf2f(h2));
    unsigned short l3 = f2bf(v.w - bf2f(h3));
    *(uint2*)&oh[i] = make_uint2((unsigned)h0 | ((unsigned)h1 << 16),
                                 (unsigned)h2 | ((unsigned)h3 << 16));
    *(uint2*)&ol[i] = make_uint2((unsigned)l0 | ((unsigned)l1 << 16),
                                 (unsigned)l2 | ((unsigned)l3 << 16));
}

// R1-proven math: P[t]=sum r^s u[s]; h[t]=w r^(L-1-t); y[t]=Re(h P)+D u; gelu.
// One wave per block (wave-private LDS, lgkmcnt-only sync).
__global__ __launch_bounds__(64) void k1_scan(const float* __restrict__ u,
                                              const float* __restrict__ Dvec,
                                              const float* __restrict__ par,
                                              unsigned short* __restrict__ YbfH,
                                              unsigned short* __restrict__ YbfL) {
    __shared__ float lds[64][66];   // [t][n]
    const int lane = threadIdx.x;
    const int pair = blockIdx.x;    // b*512 + h
    const int h = pair & 511;
    const int pidx = h * 64 + lane;
    const float rr = par[0 * PAR + pidx], ri = par[1 * PAR + pidx];
    const float vr = par[2 * PAR + pidx], vi = par[3 * PAR + pidx];
    float hr = par[4 * PAR + pidx], hi = par[5 * PAR + pidx];
    float qr = 1.f, qi = 0.f, Pr = 0.f, Pi = 0.f;
    const float Dh = Dvec[h];
    const float* ub = u + (size_t)pair * Lm;
    unsigned short* ybh = YbfH + (size_t)pair * Lm;
    unsigned short* ybl = YbfL + (size_t)pair * Lm;

    for (int ch = 0; ch < 16; ++ch) {
        float ureg = ub[ch * 64 + lane];
        #pragma unroll
        for (int t = 0; t < 64; ++t) {
            float uv = __int_as_float(
                __builtin_amdgcn_readlane(__float_as_int(ureg), t));
            Pr = fmaf(qr, uv, Pr);
            Pi = fmaf(qi, uv, Pi);
            lds[t][lane] = hr * Pr - hi * Pi;
            float tq = qr * rr - qi * ri;
            qi = fmaf(qr, ri, qi * rr);
            qr = tq;
            float th = hr * vr - hi * vi;
            hi = fmaf(hr, vi, hi * vr);
            hr = th;
        }
        asm volatile("s_waitcnt lgkmcnt(0)" ::: "memory");
        float s0 = 0.f, s1 = 0.f, s2 = 0.f, s3 = 0.f;
        #pragma unroll
        for (int n = 0; n < 64; n += 8) {
            float2 v0 = *(const float2*)&lds[lane][n + 0];
            float2 v1 = *(const float2*)&lds[lane][n + 2];
            float2 v2 = *(const float2*)&lds[lane][n + 4];
            float2 v3 = *(const float2*)&lds[lane][n + 6];
            s0 += v0.x + v0.y; s1 += v1.x + v1.y;
            s2 += v2.x + v2.y; s3 += v3.x + v3.y;
        }
        float yv = fmaf(Dh, ureg, (s0 + s1) + (s2 + s3));
        float g = 0.5f * yv * (1.0f + erff(yv * 0.70710678118654752f));
        unsigned short hb = f2bf(g);
        ybh[ch * 64 + lane] = hb;
        ybl[ch * 64 + lane] = f2bf(g - bf2f(hb));
        asm volatile("s_waitcnt lgkmcnt(0)" ::: "memory");
    }
}

// transpose [b][c][l] -> [b][l][c] per plane; blockIdx.z = plane*8 + b
__global__ __launch_bounds__(256) void k_tr(const unsigned short* __restrict__ Ybf,
                                            unsigned short* __restrict__ Ytb) {
    __shared__ unsigned short tl[64][72];
    const int t = threadIdx.x;
    const int zz = blockIdx.z;
    const int p = zz >> 3, b = zz & 7;
    const unsigned short* srcp = Ybf + (size_t)p * PLANE;
    unsigned short* dstp = Ytb + (size_t)p * PLANE;
    const int c0 = blockIdx.y * 64, l0 = blockIdx.x * 64;
    {
        const int c = t >> 2, lq = (t & 3) * 16;
        const unsigned short* src = srcp + ((size_t)(b * 512 + c0 + c)) * 1024 + l0 + lq;
        uint4 v0 = *(const uint4*)src;
        uint4 v1 = *(const uint4*)(src + 8);
        *(uint4*)&tl[c][lq] = v0;
        *(uint4*)&tl[c][lq + 8] = v1;
    }
    __syncthreads();
    {
        const int l = t >> 2, cq = (t & 3) * 16;
        unsigned int o[8];
        #pragma unroll
        for (int k = 0; k < 8; ++k)
            o[k] = (unsigned)tl[cq + 2 * k][l] | ((unsigned)tl[cq + 2 * k + 1][l] << 16);
        unsigned short* dst = dstp + ((size_t)(b * 1024 + l0 + l)) * 512 + c0 + cq;
        *(uint4*)dst = *(uint4*)&o[0];
        *(uint4*)(dst + 8) = *(uint4*)&o[4];
    }
}

// split-bf16 MFMA GEMM (hh, hl, lh) + bias/GLU/pool/dec epilogue
__global__ __launch_bounds__(256) void k2_gemm(const unsigned short* __restrict__ WbfH,
                                               const unsigned short* __restrict__ WbfL,
                                               const unsigned short* __restrict__ YtbH,
                                               const unsigned short* __restrict__ YtbL,
                                               const float* __restrict__ conv_b,
                                               const float* __restrict__ dec_w,
                                               float* __restrict__ partial) {
    __shared__ unsigned short WTh[128][40], WTl[128][40];
    __shared__ unsigned short YTh[128][40], YTl[128][40];
    __shared__ float red[4][64][20];
    const int tid = threadIdx.x, lane = tid & 63, wid = tid >> 6;
    const int b = blockIdx.z, oblk = blockIdx.y, lblk = blockIdx.x;
    const int o0 = oblk * 64, l0 = lblk * 128;
    const int fr = lane & 15, fq = lane >> 4;

    f32x4 acc[8][2] = {};

    const int srow = tid >> 1, skh = (tid & 1) * 16;
    const int grow = (srow < 64) ? (o0 + srow) : (512 + o0 + srow - 64);
    const size_t woff = (size_t)grow * 512 + skh;
    const size_t yoff = ((size_t)(b * 1024) + l0 + srow) * 512 + skh;

    for (int c0 = 0; c0 < 512; c0 += 32) {
        __syncthreads();
        uint4 wh0 = *(const uint4*)(WbfH + woff + c0);
        uint4 wh1 = *(const uint4*)(WbfH + woff + c0 + 8);
        uint4 wl0 = *(const uint4*)(WbfL + woff + c0);
        uint4 wl1 = *(const uint4*)(WbfL + woff + c0 + 8);
        uint4 yh0 = *(const uint4*)(YtbH + yoff + c0);
        uint4 yh1 = *(const uint4*)(YtbH + yoff + c0 + 8);
        uint4 yl0 = *(const uint4*)(YtbL + yoff + c0);
        uint4 yl1 = *(const uint4*)(YtbL + yoff + c0 + 8);
        *(uint4*)&WTh[srow][skh]     = wh0;
        *(uint4*)&WTh[srow][skh + 8] = wh1;
        *(uint4*)&WTl[srow][skh]     = wl0;
        *(uint4*)&WTl[srow][skh + 8] = wl1;
        *(uint4*)&YTh[srow][skh]     = yh0;
        *(uint4*)&YTh[srow][skh + 8] = yh1;
        *(uint4*)&YTl[srow][skh]     = yl0;
        *(uint4*)&YTl[srow][skh + 8] = yl1;
        __syncthreads();
        short8 b0h = *(const short8*)&YTh[wid * 32 + fr][fq * 8];
        short8 b1h = *(const short8*)&YTh[wid * 32 + 16 + fr][fq * 8];
        short8 b0l = *(const short8*)&YTl[wid * 32 + fr][fq * 8];
        short8 b1l = *(const short8*)&YTl[wid * 32 + 16 + fr][fq * 8];
        #pragma unroll
        for (int mf = 0; mf < 8; ++mf) {
            short8 ah = *(const short8*)&WTh[mf * 16 + fr][fq * 8];
            short8 al = *(const short8*)&WTl[mf * 16 + fr][fq * 8];
            acc[mf][0] = __builtin_amdgcn_mfma_f32_16x16x32_bf16(ah, b0h, acc[mf][0], 0, 0, 0);
            acc[mf][1] = __builtin_amdgcn_mfma_f32_16x16x32_bf16(ah, b1h, acc[mf][1], 0, 0, 0);
            acc[mf][0] = __builtin_amdgcn_mfma_f32_16x16x32_bf16(ah, b0l, acc[mf][0], 0, 0, 0);
            acc[mf][1] = __builtin_amdgcn_mfma_f32_16x16x32_bf16(ah, b1l, acc[mf][1], 0, 0, 0);
            acc[mf][0] = __builtin_amdgcn_mfma_f32_16x16x32_bf16(al, b0h, acc[mf][0], 0, 0, 0);
            acc[mf][1] = __builtin_amdgcn_mfma_f32_16x16x32_bf16(al, b1h, acc[mf][1], 0, 0, 0);
        }
    }

    #pragma unroll
    for (int mf = 0; mf < 4; ++mf)
        #pragma unroll
        for (int j = 0; j < 4; ++j) {
            int ol = mf * 16 + fq * 4 + j;
            float ba = conv_b[o0 + ol];
            float bb = conv_b[512 + o0 + ol];
            float s = 0.f;
            #pragma unroll
            for (int nf = 0; nf < 2; ++nf) {
                float za = acc[mf][nf][j] + ba;
                float zb = acc[mf + 4][nf][j] + bb;
                s += za / (1.f + expf(-zb));
            }
            red[wid][ol][fr] = s;
        }
    __syncthreads();
    if (tid < 64) {
        float s = 0.f;
        #pragma unroll
        for (int w = 0; w < 4; ++w) {
            float4 r0 = *(const float4*)&red[w][tid][0];
            float4 r1 = *(const float4*)&red[w][tid][4];
            float4 r2 = *(const float4*)&red[w][tid][8];
            float4 r3 = *(const float4*)&red[w][tid][12];
            s += (r0.x + r0.y + r0.z + r0.w) + (r1.x + r1.y + r1.z + r1.w)
               + (r2.x + r2.y + r2.z + r2.w) + (r3.x + r3.y + r3.z + r3.w);
        }
        float val = s * dec_w[o0 + tid] * (1.0f / 1024.0f);
        #pragma unroll
        for (int off = 32; off; off >>= 1) val += __shfl_xor(val, off);
        if (tid == 0) partial[((b * 8) + oblk) * 8 + lblk] = val;
    }
}

__global__ void k3_final(const float* __restrict__ partial,
                         const float* __restrict__ dec_b,
                         float* __restrict__ out) {
    int b = threadIdx.x;
    if (b < Bm) {
        float s = dec_b[0];
        for (int i = 0; i < 64; ++i) s += partial[b * 64 + i];
        out[b] = s;
    }
}

extern "C" void kernel_launch(void* const* d_in, const int* in_sizes, int n_in,
                              void* d_out, int out_size, void* d_ws, size_t ws_size,
                              hipStream_t stream) {
    const float* u          = (const float*)d_in[0];
    const float* log_dt     = (const float*)d_in[1];
    const float* log_A_real = (const float*)d_in[2];
    const float* A_imag     = (const float*)d_in[3];
    const float* B_real     = (const float*)d_in[4];
    const float* B_imag     = (const float*)d_in[5];
    const float* C_real     = (const float*)d_in[6];
    const float* C_imag     = (const float*)d_in[7];
    const float* Dvec       = (const float*)d_in[8];
    const float* conv_w     = (const float*)d_in[9];
    const float* conv_b     = (const float*)d_in[10];
    const float* dec_w      = (const float*)d_in[11];
    const float* dec_b      = (const float*)d_in[12];

    char* base = (char*)d_ws;
    float* par          = (float*)base;                                   // 768 KB
    unsigned short* Ybf = (unsigned short*)(base + (1u << 20));           // 16 MB (hi|lo)
    unsigned short* Ytb = (unsigned short*)(base + (1u << 20) + 16777216);// 16 MB (hi|lo)
    unsigned short* Wh  = (unsigned short*)(base + 34603008);             // 1 MB
    unsigned short* Wl  = (unsigned short*)(base + 35651584);             // 1 MB
    float* partial      = (float*)(base + 36700160);                      // 2 KB
    float* out          = (float*)d_out;

    unsigned short* YbfH = Ybf;
    unsigned short* YbfL = Ybf + PLANE;
    unsigned short* YtbH = Ytb;
    unsigned short* YtbL = Ytb + PLANE;

    k0_params<<<128, 256, 0, stream>>>(log_dt, log_A_real, A_imag, B_real,
                                       B_imag, C_real, C_imag, par);
    k_cvt<<<512, 256, 0, stream>>>(conv_w, Wh, Wl);
    k1_scan<<<4096, 64, 0, stream>>>(u, Dvec, par, YbfH, YbfL);
    k_tr<<<dim3(16, 8, 16), 256, 0, stream>>>(Ybf, Ytb);
    k2_gemm<<<dim3(8, 8, 8), 256, 0, stream>>>(Wh, Wl, YtbH, YtbL, conv_b, dec_w, partial);
    k3_final<<<1, 64, 0, stream>>>(partial, dec_b, out);
}

// Round 5
// 100.431 us; speedup vs baseline: 2.7497x; 1.9562x over previous
//
#include <hip/hip_runtime.h>
#include <hip/hip_bf16.h>
#include <math.h>

typedef __attribute__((ext_vector_type(8))) short short8;
typedef __attribute__((ext_vector_type(4))) float f32x4;

constexpr int Hm = 512, Lm = 1024, Bm = 8;
constexpr int PAR = Hm * 64;
constexpr size_t PLANE = (size_t)Bm * Hm * Lm;   // 4194304 ushorts per plane

static __device__ __forceinline__ unsigned short f2bf(float f) {
    __hip_bfloat16 h = __float2bfloat16(f);
    return *reinterpret_cast<unsigned short*>(&h);
}
static __device__ __forceinline__ float bf2f(unsigned short u) {
    return __uint_as_float((unsigned)u << 16);
}
static __device__ __forceinline__ uint2 pack4(const unsigned short* x) {
    return make_uint2((unsigned)x[0] | ((unsigned)x[1] << 16),
                      (unsigned)x[2] | ((unsigned)x[3] << 16));
}

// par planes: 0 rr, 1 ri, 2 wr, 3 wi, 4 r64r, 5 r64i
__global__ void k0_params(const float* __restrict__ log_dt,
                          const float* __restrict__ log_A_real,
                          const float* __restrict__ A_imag,
                          const float* __restrict__ B_real,
                          const float* __restrict__ B_imag,
                          const float* __restrict__ C_real,
                          const float* __restrict__ C_imag,
                          float* __restrict__ par) {
    int idx = blockIdx.x * blockDim.x + threadIdx.x;
    if (idx >= PAR) return;
    int h = idx >> 6;
    double dt = exp((double)log_dt[h]);
    double Ar = -exp((double)log_A_real[idx]);
    double Ai = (double)A_imag[idx];
    double ar = Ar * dt, ai = Ai * dt;          // dtA
    double er = exp(ar);
    double rr = er * cos(ai), ri = er * sin(ai);        // r
    double nr = rr - 1.0, ni = ri;
    double den = Ar * Ar + Ai * Ai;
    double qr = (nr * Ar + ni * Ai) / den;
    double qi = (ni * Ar - nr * Ai) / den;
    double Br = (double)B_real[idx], Bi = (double)B_imag[idx];
    double bbr = qr * Br - qi * Bi, bbi = qr * Bi + qi * Br;
    double Cr = (double)C_real[idx], Ci = (double)C_imag[idx];
    double wr = Cr * bbr - Ci * bbi, wi = Cr * bbi + Ci * bbr;
    double e64 = exp(ar * 64.0);
    double p64 = ai * 64.0;
    par[0 * PAR + idx] = (float)rr;
    par[1 * PAR + idx] = (float)ri;
    par[2 * PAR + idx] = (float)wr;
    par[3 * PAR + idx] = (float)wi;
    par[4 * PAR + idx] = (float)(e64 * cos(p64));
    par[5 * PAR + idx] = (float)(e64 * sin(p64));
}

// conv_w f32 -> hi/lo bf16 planes
__global__ void k_cvt(const float* __restrict__ w,
                      unsigned short* __restrict__ oh,
                      unsigned short* __restrict__ ol) {
    int i = (blockIdx.x * 256 + threadIdx.x) * 4;
    float4 v = *(const float4*)&w[i];
    unsigned short h0 = f2bf(v.x), h1 = f2bf(v.y), h2 = f2bf(v.z), h3 = f2bf(v.w);
    unsigned short l0 = f2bf(v.x - bf2f(h0));
    unsigned short l1 = f2bf(v.y - bf2f(h1));
    unsigned short l2 = f2bf(v.z - bf2f(h2));
    unsigned short l3 = f2bf(v.w - bf2f(h3));
    *(uint2*)&oh[i] = make_uint2((unsigned)h0 | ((unsigned)h1 << 16),
                                 (unsigned)h2 | ((unsigned)h3 << 16));
    *(uint2*)&ol[i] = make_uint2((unsigned)l0 | ((unsigned)l1 << 16),
                                 (unsigned)l2 | ((unsigned)l3 << 16));
}

// Toeplitz block-conv via MFMA. One block per h. 4 waves.
// y_i (64x8) = sum_d T_d (64x64) @ u_{i-d} (64x8); N=16 packs (2 i-chunks x 8 b).
// LDS map (71680 B):
//   Ks:   [0, 4096)              K[h][0..1024) f32
//   uh:   [4096, 24576)          [16 jc][2 ks][8 b][40] ushorts (hi)
//   ul:   [24576, 45056)         same (lo)
//   Th:   [45056, 55296)         [2 ks][64 t'][40] ushorts (hi)
//   Tl:   [55296, 65536)         same (lo)
//   phase0 overlay at [4096, 71680): per-wave kl[64][66] f32
__global__ __launch_bounds__(256) void k_tconv(const float* __restrict__ u,
                                               const float* __restrict__ Dvec,
                                               const float* __restrict__ par,
                                               unsigned short* __restrict__ YbfH,
                                               unsigned short* __restrict__ YbfL) {
    __shared__ __align__(16) char smem[71680];
    float* Ks = (float*)smem;
    unsigned short* uh = (unsigned short*)(smem + 4096);
    unsigned short* ul = uh + 10240;
    unsigned short* Th = (unsigned short*)(smem + 45056);
    unsigned short* Tl = Th + 5120;

    const int tid = threadIdx.x, lane = tid & 63, wid = tid >> 6;
    const int h = blockIdx.x;
    const int fr = lane & 15, fq = lane >> 4;
    const short8 z8 = {};

    // ---- phase 0: K[h][j] = Re(sum_n w_n r_n^j) ----
    {
        float* kl = (float*)(smem + 4096) + wid * 4224;   // [64][66]
        const int pidx = h * 64 + lane;
        const float rrf = par[0 * PAR + pidx], rif = par[1 * PAR + pidx];
        float pr = par[2 * PAR + pidx], pi = par[3 * PAR + pidx];   // w
        float br = par[4 * PAR + pidx], bi = par[5 * PAR + pidx];   // r^64
        int cc = wid * 4;
        while (cc) {   // p = w * (r^64)^(4*wid)
            if (cc & 1) { float t_ = pr * br - pi * bi; pi = fmaf(pr, bi, pi * br); pr = t_; }
            float t2 = br * br - bi * bi; bi = 2.f * br * bi; br = t2;
            cc >>= 1;
        }
        for (int q = 0; q < 4; ++q) {
            #pragma unroll
            for (int j = 0; j < 64; ++j) {
                kl[j * 66 + lane] = pr;
                float t_ = pr * rrf - pi * rif; pi = fmaf(pr, rif, pi * rrf); pr = t_;
            }
            asm volatile("s_waitcnt lgkmcnt(0)" ::: "memory");
            float s0 = 0.f, s1 = 0.f;
            #pragma unroll
            for (int n = 0; n < 64; n += 4) {
                float2 a = *(const float2*)&kl[lane * 66 + n];
                float2 b2 = *(const float2*)&kl[lane * 66 + n + 2];
                s0 += a.x + a.y; s1 += b2.x + b2.y;
            }
            Ks[(wid * 4 + q) * 64 + lane] = s0 + s1;
            asm volatile("s_waitcnt lgkmcnt(0)" ::: "memory");
        }
    }
    __syncthreads();

    // ---- phase 1: stage u -> bf16 hi/lo B-operand layout ----
    {
        const int b = tid >> 5, l32 = tid & 31;
        const float* ub = u + ((size_t)(b * 512 + h)) * 1024;
        #pragma unroll
        for (int g = 0; g < 8; ++g) {
            int s = l32 * 4 + g * 128;
            float4 v = *(const float4*)&ub[s];
            unsigned short th[4], tl[4];
            th[0] = f2bf(v.x); tl[0] = f2bf(v.x - bf2f(th[0]));
            th[1] = f2bf(v.y); tl[1] = f2bf(v.y - bf2f(th[1]));
            th[2] = f2bf(v.z); tl[2] = f2bf(v.z - bf2f(th[2]));
            th[3] = f2bf(v.w); tl[3] = f2bf(v.w - bf2f(th[3]));
            int jc = s >> 6, ks = (s >> 5) & 1, k0 = s & 31;
            int off = ((jc * 2 + ks) * 8 + b) * 40 + k0;
            *(uint2*)&uh[off] = pack4(th);
            *(uint2*)&ul[off] = pack4(tl);
        }
    }
    __syncthreads();

    const float Dh = Dvec[h];
    f32x4 acc[2][4] = {};          // [pair][mf]
    const int i_lo[2] = { wid, 7 - wid };
    const int i_hi[2] = { wid + 8, 15 - wid };

    // ---- phase 2: d-loop ----
    for (int d = 0; d < 16; ++d) {
        {   // build T_d: T[t'][s'] = Kf[64d + t'-s'], Kf[lag] = Ks[1023-lag]
            const int tp = tid >> 2, s0 = (tid & 3) * 16;
            const int base = 1023 - d * 64 - tp + s0;
            unsigned short th[16], tl[16];
            #pragma unroll
            for (int k = 0; k < 16; ++k) {
                int lag = d * 64 + tp - s0 - k;
                float v = (lag >= 0) ? Ks[base + k] : 0.f;
                unsigned short hh = f2bf(v);
                th[k] = hh; tl[k] = f2bf(v - bf2f(hh));
            }
            int off = ((s0 >> 5) * 64 + tp) * 40 + (s0 & 31);
            *(uint2*)&Th[off]     = pack4(th + 0);
            *(uint2*)&Th[off + 4] = pack4(th + 4);
            *(uint2*)&Th[off + 8] = pack4(th + 8);
            *(uint2*)&Th[off + 12] = pack4(th + 12);
            *(uint2*)&Tl[off]     = pack4(tl + 0);
            *(uint2*)&Tl[off + 4] = pack4(tl + 4);
            *(uint2*)&Tl[off + 8] = pack4(tl + 8);
            *(uint2*)&Tl[off + 12] = pack4(tl + 12);
        }
        __syncthreads();

        short8 Ah[4][2], Al[4][2];
        #pragma unroll
        for (int mf = 0; mf < 4; ++mf)
            #pragma unroll
            for (int ks = 0; ks < 2; ++ks) {
                int ao = (ks * 64 + mf * 16 + fr) * 40 + fq * 8;
                Ah[mf][ks] = *(const short8*)&Th[ao];
                Al[mf][ks] = *(const short8*)&Tl[ao];
            }
        #pragma unroll
        for (int p = 0; p < 2; ++p) {
            if (i_hi[p] < d) continue;
            int jmine = ((fr >> 3) ? i_hi[p] : i_lo[p]) - d;
            bool vv = jmine >= 0;
            int ja = vv ? jmine : 0;
            #pragma unroll
            for (int ks = 0; ks < 2; ++ks) {
                int uoff = ((ja * 2 + ks) * 8 + (fr & 7)) * 40 + fq * 8;
                short8 bh = *(const short8*)&uh[uoff];
                short8 bl = *(const short8*)&ul[uoff];
                if (!vv) { bh = z8; bl = z8; }
                #pragma unroll
                for (int mf = 0; mf < 4; ++mf) {
                    acc[p][mf] = __builtin_amdgcn_mfma_f32_16x16x32_bf16(Ah[mf][ks], bh, acc[p][mf], 0, 0, 0);
                    acc[p][mf] = __builtin_amdgcn_mfma_f32_16x16x32_bf16(Ah[mf][ks], bl, acc[p][mf], 0, 0, 0);
                    acc[p][mf] = __builtin_amdgcn_mfma_f32_16x16x32_bf16(Al[mf][ks], bh, acc[p][mf], 0, 0, 0);
                }
            }
        }
        __syncthreads();
    }

    // ---- epilogue: y + D*u, gelu, hi/lo write ----
    #pragma unroll
    for (int p = 0; p < 2; ++p) {
        const int i_mine = (fr >> 3) ? i_hi[p] : i_lo[p];
        const int b = fr & 7;
        unsigned short* dsth = YbfH + ((size_t)(b * 512 + h)) * 1024 + i_mine * 64;
        unsigned short* dstl = YbfL + ((size_t)(b * 512 + h)) * 1024 + i_mine * 64;
        #pragma unroll
        for (int mf = 0; mf < 4; ++mf) {
            unsigned short oh[4], ol[4];
            #pragma unroll
            for (int j = 0; j < 4; ++j) {
                int tp = mf * 16 + fq * 4 + j;
                int uoff = ((i_mine * 2 + (tp >> 5)) * 8 + b) * 40 + (tp & 31);
                float uv = bf2f(uh[uoff]) + bf2f(ul[uoff]);
                float y = acc[p][mf][j] + Dh * uv;
                float g = 0.5f * y * (1.0f + erff(y * 0.70710678118654752f));
                oh[j] = f2bf(g);
                ol[j] = f2bf(g - bf2f(oh[j]));
            }
            int toff = mf * 16 + fq * 4;
            *(uint2*)&dsth[toff] = pack4(oh);
            *(uint2*)&dstl[toff] = pack4(ol);
        }
    }
}

// transpose [b][c][l] -> [b][l][c] per plane; blockIdx.z = plane*8 + b
__global__ __launch_bounds__(256) void k_tr(const unsigned short* __restrict__ Ybf,
                                            unsigned short* __restrict__ Ytb) {
    __shared__ unsigned short tl[64][72];
    const int t = threadIdx.x;
    const int zz = blockIdx.z;
    const int p = zz >> 3, b = zz & 7;
    const unsigned short* srcp = Ybf + (size_t)p * PLANE;
    unsigned short* dstp = Ytb + (size_t)p * PLANE;
    const int c0 = blockIdx.y * 64, l0 = blockIdx.x * 64;
    {
        const int c = t >> 2, lq = (t & 3) * 16;
        const unsigned short* src = srcp + ((size_t)(b * 512 + c0 + c)) * 1024 + l0 + lq;
        uint4 v0 = *(const uint4*)src;
        uint4 v1 = *(const uint4*)(src + 8);
        *(uint4*)&tl[c][lq] = v0;
        *(uint4*)&tl[c][lq + 8] = v1;
    }
    __syncthreads();
    {
        const int l = t >> 2, cq = (t & 3) * 16;
        unsigned int o[8];
        #pragma unroll
        for (int k = 0; k < 8; ++k)
            o[k] = (unsigned)tl[cq + 2 * k][l] | ((unsigned)tl[cq + 2 * k + 1][l] << 16);
        unsigned short* dst = dstp + ((size_t)(b * 1024 + l0 + l)) * 512 + c0 + cq;
        *(uint4*)dst = *(uint4*)&o[0];
        *(uint4*)(dst + 8) = *(uint4*)&o[4];
    }
}

// split-bf16 MFMA GEMM (hh, hl, lh) + bias/GLU/pool/dec epilogue
__global__ __launch_bounds__(256) void k2_gemm(const unsigned short* __restrict__ WbfH,
                                               const unsigned short* __restrict__ WbfL,
                                               const unsigned short* __restrict__ YtbH,
                                               const unsigned short* __restrict__ YtbL,
                                               const float* __restrict__ conv_b,
                                               const float* __restrict__ dec_w,
                                               float* __restrict__ partial) {
    __shared__ unsigned short WTh[128][40], WTl[128][40];
    __shared__ unsigned short YTh[128][40], YTl[128][40];
    __shared__ float red[4][64][20];
    const int tid = threadIdx.x, lane = tid & 63, wid = tid >> 6;
    const int b = blockIdx.z, oblk = blockIdx.y, lblk = blockIdx.x;
    const int o0 = oblk * 64, l0 = lblk * 128;
    const int fr = lane & 15, fq = lane >> 4;

    f32x4 acc[8][2] = {};

    const int srow = tid >> 1, skh = (tid & 1) * 16;
    const int grow = (srow < 64) ? (o0 + srow) : (512 + o0 + srow - 64);
    const size_t woff = (size_t)grow * 512 + skh;
    const size_t yoff = ((size_t)(b * 1024) + l0 + srow) * 512 + skh;

    for (int c0 = 0; c0 < 512; c0 += 32) {
        __syncthreads();
        uint4 wh0 = *(const uint4*)(WbfH + woff + c0);
        uint4 wh1 = *(const uint4*)(WbfH + woff + c0 + 8);
        uint4 wl0 = *(const uint4*)(WbfL + woff + c0);
        uint4 wl1 = *(const uint4*)(WbfL + woff + c0 + 8);
        uint4 yh0 = *(const uint4*)(YtbH + yoff + c0);
        uint4 yh1 = *(const uint4*)(YtbH + yoff + c0 + 8);
        uint4 yl0 = *(const uint4*)(YtbL + yoff + c0);
        uint4 yl1 = *(const uint4*)(YtbL + yoff + c0 + 8);
        *(uint4*)&WTh[srow][skh]     = wh0;
        *(uint4*)&WTh[srow][skh + 8] = wh1;
        *(uint4*)&WTl[srow][skh]     = wl0;
        *(uint4*)&WTl[srow][skh + 8] = wl1;
        *(uint4*)&YTh[srow][skh]     = yh0;
        *(uint4*)&YTh[srow][skh + 8] = yh1;
        *(uint4*)&YTl[srow][skh]     = yl0;
        *(uint4*)&YTl[srow][skh + 8] = yl1;
        __syncthreads();
        short8 b0h = *(const short8*)&YTh[wid * 32 + fr][fq * 8];
        short8 b1h = *(const short8*)&YTh[wid * 32 + 16 + fr][fq * 8];
        short8 b0l = *(const short8*)&YTl[wid * 32 + fr][fq * 8];
        short8 b1l = *(const short8*)&YTl[wid * 32 + 16 + fr][fq * 8];
        #pragma unroll
        for (int mf = 0; mf < 8; ++mf) {
            short8 ah = *(const short8*)&WTh[mf * 16 + fr][fq * 8];
            short8 al = *(const short8*)&WTl[mf * 16 + fr][fq * 8];
            acc[mf][0] = __builtin_amdgcn_mfma_f32_16x16x32_bf16(ah, b0h, acc[mf][0], 0, 0, 0);
            acc[mf][1] = __builtin_amdgcn_mfma_f32_16x16x32_bf16(ah, b1h, acc[mf][1], 0, 0, 0);
            acc[mf][0] = __builtin_amdgcn_mfma_f32_16x16x32_bf16(ah, b0l, acc[mf][0], 0, 0, 0);
            acc[mf][1] = __builtin_amdgcn_mfma_f32_16x16x32_bf16(ah, b1l, acc[mf][1], 0, 0, 0);
            acc[mf][0] = __builtin_amdgcn_mfma_f32_16x16x32_bf16(al, b0h, acc[mf][0], 0, 0, 0);
            acc[mf][1] = __builtin_amdgcn_mfma_f32_16x16x32_bf16(al, b1h, acc[mf][1], 0, 0, 0);
        }
    }

    #pragma unroll
    for (int mf = 0; mf < 4; ++mf)
        #pragma unroll
        for (int j = 0; j < 4; ++j) {
            int ol = mf * 16 + fq * 4 + j;
            float ba = conv_b[o0 + ol];
            float bb = conv_b[512 + o0 + ol];
            float s = 0.f;
            #pragma unroll
            for (int nf = 0; nf < 2; ++nf) {
                float za = acc[mf][nf][j] + ba;
                float zb = acc[mf + 4][nf][j] + bb;
                s += za / (1.f + expf(-zb));
            }
            red[wid][ol][fr] = s;
        }
    __syncthreads();
    if (tid < 64) {
        float s = 0.f;
        #pragma unroll
        for (int w = 0; w < 4; ++w) {
            float4 r0 = *(const float4*)&red[w][tid][0];
            float4 r1 = *(const float4*)&red[w][tid][4];
            float4 r2 = *(const float4*)&red[w][tid][8];
            float4 r3 = *(const float4*)&red[w][tid][12];
            s += (r0.x + r0.y + r0.z + r0.w) + (r1.x + r1.y + r1.z + r1.w)
               + (r2.x + r2.y + r2.z + r2.w) + (r3.x + r3.y + r3.z + r3.w);
        }
        float val = s * dec_w[o0 + tid] * (1.0f / 1024.0f);
        #pragma unroll
        for (int off = 32; off; off >>= 1) val += __shfl_xor(val, off);
        if (tid == 0) partial[((b * 8) + oblk) * 8 + lblk] = val;
    }
}

__global__ void k3_final(const float* __restrict__ partial,
                         const float* __restrict__ dec_b,
                         float* __restrict__ out) {
    int b = threadIdx.x;
    if (b < Bm) {
        float s = dec_b[0];
        for (int i = 0; i < 64; ++i) s += partial[b * 64 + i];
        out[b] = s;
    }
}

extern "C" void kernel_launch(void* const* d_in, const int* in_sizes, int n_in,
                              void* d_out, int out_size, void* d_ws, size_t ws_size,
                              hipStream_t stream) {
    const float* u          = (const float*)d_in[0];
    const float* log_dt     = (const float*)d_in[1];
    const float* log_A_real = (const float*)d_in[2];
    const float* A_imag     = (const float*)d_in[3];
    const float* B_real     = (const float*)d_in[4];
    const float* B_imag     = (const float*)d_in[5];
    const float* C_real     = (const float*)d_in[6];
    const float* C_imag     = (const float*)d_in[7];
    const float* Dvec       = (const float*)d_in[8];
    const float* conv_w     = (const float*)d_in[9];
    const float* conv_b     = (const float*)d_in[10];
    const float* dec_w      = (const float*)d_in[11];
    const float* dec_b      = (const float*)d_in[12];

    char* base = (char*)d_ws;
    float* par          = (float*)base;                                   // 768 KB
    unsigned short* Ybf = (unsigned short*)(base + 786432);               // 16 MB (hi|lo)
    unsigned short* Ytb = (unsigned short*)(base + 786432 + 16777216);    // 16 MB (hi|lo)
    unsigned short* Wh  = (unsigned short*)(base + 34340864);             // 1 MB
    unsigned short* Wl  = (unsigned short*)(base + 35389440);             // 1 MB
    float* partial      = (float*)(base + 36438016);                      // 2 KB
    float* out          = (float*)d_out;

    unsigned short* YbfH = Ybf;
    unsigned short* YbfL = Ybf + PLANE;
    unsigned short* YtbH = Ytb;
    unsigned short* YtbL = Ytb + PLANE;

    k0_params<<<128, 256, 0, stream>>>(log_dt, log_A_real, A_imag, B_real,
                                       B_imag, C_real, C_imag, par);
    k_cvt<<<512, 256, 0, stream>>>(conv_w, Wh, Wl);
    k_tconv<<<512, 256, 0, stream>>>(u, Dvec, par, YbfH, YbfL);
    k_tr<<<dim3(16, 8, 16), 256, 0, stream>>>(Ybf, Ytb);
    k2_gemm<<<dim3(8, 8, 8), 256, 0, stream>>>(Wh, Wl, YtbH, YtbL, conv_b, dec_w, partial);
    k3_final<<<1, 64, 0, stream>>>(partial, dec_b, out);
}